// Round 8
// baseline (5231.327 us; speedup 1.0000x reference)
//
#include <hip/hip_runtime.h>
#include <cmath>
#include <cstring>
#include <vector>

// ---------------------------------------------------------------------------
// S2ConvNet forward. Round 5:
//  - inverse 2D DFT split into two batched GEMM-shaped kernels (k5a over mi,
//    k5b over ni + bias/relu) reading k4's native [(mi,ni)][row] layout;
//    ktr removed from the idft path. Round-4 k5_idft was latency-bound:
//    48KB LDS -> 3 blocks/CU, 1ms/dispatch, ~4ms of the 5.4ms total.
// ---------------------------------------------------------------------------

// ======================= table-generation kernels ==========================

__global__ void kg_idx(int4* __restrict__ LMN28, int4* __restrict__ LMN14,
                       int* __restrict__ IDX1) {
  int l = blockIdx.x;                 // 0..27
  int L = 2*l + 1, ofs = l*(4*l*l - 1)/3;
  for (int i = threadIdx.x; i < L*L; i += blockDim.x) {
    int a = i / L, c = i - a*L;
    int4 v = make_int4(l, a - l, c - l, 0);
    LMN28[ofs + i] = v;
    if (l < 14) LMN14[ofs + i] = v;
  }
  for (int a = threadIdx.x; a < L; a += blockDim.x)
    IDX1[l*l + a] = (a - l) + 27;
}

__global__ void kg_tw(float2* __restrict__ E224, float2* __restrict__ EF56,
                      float2* __restrict__ EI56, float2* __restrict__ EF28,
                      float2* __restrict__ EI28) {
  int t = blockIdx.x*256 + threadIdx.x;
  const float TP = 6.283185307179586f;
  if (t < 12320) {                      // E224: 55 x 224, fwd
    int mi = t/224, a = t - mi*224;
    int r = ((mi - 27)*a) % 224;
    float ang = -TP*r/224.f;
    E224[t] = make_float2(cosf(ang), sinf(ang)); return;
  }
  t -= 12320;
  if (t < 1512) {                       // EF56: 27 x 56, fwd
    int ki = t/56, g = t - ki*56;
    int r = ((ki - 13)*g) % 56;
    float ang = -TP*r/56.f;
    EF56[t] = make_float2(cosf(ang), sinf(ang)); return;
  }
  t -= 1512;
  if (t < 3080) {                       // EI56: 56 x 55, inv
    int a = t/55, mi = t - a*55;
    int r = ((mi - 27)*a) % 56;
    float ang = TP*r/56.f;
    EI56[t] = make_float2(cosf(ang), sinf(ang)); return;
  }
  t -= 3080;
  if (t < 756) {                        // EF28: 27 x 28, fwd
    int ki = t/28, g = t - ki*28;
    int r = ((ki - 13)*g) % 28;
    float ang = -TP*r/28.f;
    EF28[t] = make_float2(cosf(ang), sinf(ang)); return;
  }
  t -= 756;
  if (t < 756) {                        // EI28: 28 x 27, inv
    int a = t/27, mi = t - a*27;
    int r = ((mi - 13)*a) % 28;
    float ang = TP*r/28.f;
    EI28[t] = make_float2(cosf(ang), sinf(ang));
  }
}

// Wigner-d tables from eigen-seed: d[a][c](beta) = sum_k V[a,k]V[c,k]*f(beta*lam_k)
// mode 0: s2 table (spec = l*l+a, c = l, weight QW[j])
// mode 1: weight (2l+1)   mode 2: weight QW[j]
__global__ void kg_wig(const float* __restrict__ VT, const float* __restrict__ LAM,
                       const float* __restrict__ QW, const int4* __restrict__ LMN,
                       float* __restrict__ OUT, int NB, int mode) {
  int spec = blockIdx.x;
  int l, a, c;
  if (mode == 0) {
    l = 0; while ((l+1)*(l+1) <= spec) ++l;
    a = spec - l*l; c = l;
  } else {
    int4 t4 = LMN[spec];
    l = t4.x; a = t4.y + l; c = t4.z + l;
  }
  int n = 2*l + 1;
  const float* V = VT + (size_t)l*(4*l*l - 1)/3;
  const float* lam = LAM + l*l;
  int j = threadIdx.x;
  if (j >= NB) return;
  float be = (j + 0.5f)*(float)M_PI/NB;
  float sc = 0.f, ss = 0.f;
  for (int k = 0; k < n; ++k) {
    float vv = V[a*n + k]*V[c*n + k];
    float x = be*lam[k];
    sc += vv*cosf(x); ss += vv*sinf(x);
  }
  int p = (a - c) & 3;
  float dv = (p==0) ? sc : (p==1) ? -ss : (p==2) ? -sc : ss;
  float w = (mode == 1) ? (float)n : QW[j];
  OUT[(size_t)spec*NB + j] = w*dv;
}

// ============================ pipeline kernels =============================

// ---- Stage 1a: DFT over alpha (224 -> 55 freqs), real input --------------
__global__ void k1_dft_alpha(const float* __restrict__ x,
                             const float2* __restrict__ E,
                             float2* __restrict__ XF) {
  int row = blockIdx.x;                       // z*224 + beta
  __shared__ float r[224];
  for (int i = threadIdx.x; i < 224; i += 64) r[i] = x[(size_t)row*224 + i];
  __syncthreads();
  int mi = threadIdx.x;
  if (mi < 55) {
    float2 acc = make_float2(0.f, 0.f);
    for (int a = 0; a < 224; ++a) {
      float v = r[a];
      float2 e = E[mi*224 + a];
      acc.x += v*e.x; acc.y += v*e.y;
    }
    XF[(size_t)row*55 + mi] = acc;
  }
}

// ---- Stage 1b: S2 Wigner contraction over beta ---------------------------
__global__ void k2_s2wig(const float2* __restrict__ XF,
                         const float* __restrict__ W,
                         const int* __restrict__ IDX,
                         float2* __restrict__ XS) {
  int lm = blockIdx.x;
  int z = threadIdx.x;
  if (z >= 12) return;
  int mi = IDX[lm];
  float2 acc = make_float2(0.f, 0.f);
  for (int b = 0; b < 224; ++b) {
    float w = W[(size_t)lm*224 + b];
    float2 v = XF[((size_t)z*224 + b)*55 + mi];
    acc.x += w*v.x; acc.y += w*v.y;
  }
  XS[lm*12 + z] = acc;
}

// ---- Layer-1 combine ------------------------------------------------------
__global__ void k3_combine1(const float2* __restrict__ XS,
                            const float2* __restrict__ W1,
                            const int4* __restrict__ LMN,
                            float2* __restrict__ ZS) {
  int r = blockIdx.x;
  int4 t = LMN[r];
  int l = t.x, m = t.y, n = t.z;
  int sm = l*l + l + m, sn = l*l + l + n;
  int zb = threadIdx.x >> 5, o = threadIdx.x & 31;
  float2 acc = make_float2(0.f, 0.f);
  #pragma unroll
  for (int i = 0; i < 3; ++i) {
    float2 xv = XS[sm*12 + zb*3 + i];
    float2 wv = W1[(sn*3 + i)*32 + o];
    acc.x += xv.x*wv.x + xv.y*wv.y;   // xv * conj(wv)
    acc.y += xv.y*wv.x - xv.x*wv.y;
  }
  ZS[(size_t)r*128 + threadIdx.x] = acc;
}

// ---- Inverse Wigner -------------------------------------------------------
template<int NB, int NL>
__global__ void k4_wiginv(const float2* __restrict__ ZS,
                          const float* __restrict__ WT,
                          float2* __restrict__ Gp,
                          int Ztot, int z0, int ZC) {
  constexpr int NF = 2*NL - 1;
  constexpr int NJ = (NB + 7)/8;
  int bx = blockIdx.x;
  int mi = bx / NF, ni = bx % NF;
  int m = mi - (NL-1), n = ni - (NL-1);
  int zl = blockIdx.y*32 + (threadIdx.x & 31);
  int g  = threadIdx.x >> 5;     // 0..7
  float2 acc[NJ];
  #pragma unroll
  for (int j = 0; j < NJ; ++j) acc[j] = make_float2(0.f, 0.f);
  int am = m < 0 ? -m : m, an = n < 0 ? -n : n;
  int lmin = am > an ? am : an;
  for (int l = lmin; l < NL; ++l) {
    int L = 2*l + 1;
    int spec = l*(4*l*l - 1)/3 + (m + l)*L + (n + l);
    float2 zv = ZS[(size_t)spec*Ztot + z0 + zl];
    #pragma unroll
    for (int j = 0; j < NJ; ++j) {
      int b = g + j*8;
      if (b < NB) {
        float w = WT[(size_t)spec*NB + b];
        acc[j].x += w*zv.x; acc[j].y += w*zv.y;
      }
    }
  }
  size_t base = (size_t)bx * ((size_t)ZC*NB) + (size_t)zl*NB;
  #pragma unroll
  for (int j = 0; j < NJ; ++j) {
    int b = g + j*8;
    if (b < NB) Gp[base + b] = acc[j];
  }
}

// ---- generic complex 2D transpose [R][C] -> [C][R] ------------------------
__global__ void ktr(const float2* __restrict__ in, float2* __restrict__ out,
                    int R, int C) {
  __shared__ float2 t[32][33];
  int c0 = blockIdx.x*32, r0 = blockIdx.y*32;
  for (int j = threadIdx.y; j < 32; j += 8) {
    int rr = r0 + j, cc = c0 + threadIdx.x;
    if (rr < R && cc < C) t[j][threadIdx.x] = in[(size_t)rr*C + cc];
  }
  __syncthreads();
  for (int j = threadIdx.y; j < 32; j += 8) {
    int rr = r0 + threadIdx.x, cc = c0 + j;
    if (rr < R && cc < C) out[(size_t)cc*R + rr] = t[threadIdx.x][j];
  }
}

// ---- idft stage A: contract mi. T2[(a,ni)][row] = sum_mi EI[a,mi]*G[(mi,ni)][row]
template<int NF, int NA>
__global__ __launch_bounds__(256)
void k5a_idft(const float2* __restrict__ G, const float2* __restrict__ EI,
              float2* __restrict__ T2, int rowsC) {
  int ni = blockIdx.x;
  int at = blockIdx.y;
  int row = blockIdx.z*256 + threadIdx.x;
  if (row >= rowsC) return;
  float2 acc[8];
  #pragma unroll
  for (int u = 0; u < 8; ++u) acc[u] = make_float2(0.f, 0.f);
  const float2* gp = G + (size_t)ni*rowsC + row;
  for (int mi = 0; mi < NF; ++mi) {
    float2 gv = gp[(size_t)mi*NF*rowsC];
    #pragma unroll
    for (int u = 0; u < 8; ++u) {
      int a = at*8 + u; if (a >= NA) a = NA-1;       // clamp (result discarded)
      float2 e = EI[a*NF + mi];                      // block-uniform -> s_load
      acc[u].x += e.x*gv.x - e.y*gv.y;
      acc[u].y += e.x*gv.y + e.y*gv.x;
    }
  }
  #pragma unroll
  for (int u = 0; u < 8; ++u) {
    int a = at*8 + u;
    if (a < NA) T2[((size_t)a*NF + ni)*rowsC + row] = acc[u];
  }
}

// ---- idft stage B: contract ni, take Re, + bias + relu --------------------
// H[z,beta,a,g] = Re sum_ni T2[(a,ni)][row] * EI[g,ni] ; row = zl*NB+beta
template<int NF, int NA>
__global__ __launch_bounds__(256)
void k5b_idft(const float2* __restrict__ T2, const float2* __restrict__ EI,
              const float* __restrict__ bias, float* __restrict__ H,
              int NB, int z0, int Cout, int rowsC) {
  constexpr int NAP = ((NA + 15)/16)*16;
  constexpr int NIT = NAP/16;
  __shared__ float2 EIs[NAP*NF];
  __shared__ float2 Ts[NF][16];
  int a = blockIdx.x;
  int row0 = blockIdx.y*16;
  int t = threadIdx.x;
  for (int i = t; i < NAP*NF; i += 256) {
    int g = i / NF;
    EIs[i] = (g < NA) ? EI[i] : make_float2(0.f, 0.f);
  }
  for (int i = t; i < NF*16; i += 256) {
    int ni = i >> 4, r = i & 15;
    int row = row0 + r;
    Ts[ni][r] = (row < rowsC) ? T2[((size_t)a*NF + ni)*rowsC + row]
                              : make_float2(0.f, 0.f);
  }
  __syncthreads();
  int r = t & 15, g0 = t >> 4;
  int row = row0 + r;
  if (row >= rowsC) return;
  int zl = row / NB, beta = row - zl*NB;
  int z = z0 + zl;
  float bv = bias[z % Cout];
  float facc[NIT];
  #pragma unroll
  for (int it = 0; it < NIT; ++it) facc[it] = 0.f;
  for (int ni = 0; ni < NF; ++ni) {
    float2 tv = Ts[ni][r];
    #pragma unroll
    for (int it = 0; it < NIT; ++it) {
      float2 e = EIs[(g0 + 16*it)*NF + ni];
      facc[it] += e.x*tv.x - e.y*tv.y;
    }
  }
  size_t hb2 = ((size_t)z*NB + beta)*(size_t)(NA*NA) + (size_t)a*NA;
  #pragma unroll
  for (int it = 0; it < NIT; ++it) {
    int g = g0 + 16*it;
    if (g < NA) H[hb2 + g] = fmaxf(facc[it] + bv, 0.f);
  }
}

// ---- fused forward 2D DFT (g then a), real input --------------------------
template<int NA, int NF>
__global__ void k67_dftfwd(const float* __restrict__ H,
                           const float2* __restrict__ EF,
                           float2* __restrict__ Xfp,
                           int NB, int z0, int ZC) {
  int row = blockIdx.x;                 // zl*NB + beta
  int zl = row / NB, beta = row - zl*NB;
  int z = z0 + zl;
  __shared__ float r[NA*NA];
  __shared__ float2 xa[NA*NF];
  for (int i = threadIdx.x; i < NA*NA; i += blockDim.x)
    r[i] = H[((size_t)z*NB + beta)*NA*NA + i];
  __syncthreads();
  for (int idx = threadIdx.x; idx < NA*NF; idx += blockDim.x) {
    int a = idx / NF, ki = idx - a*NF;
    float2 acc = make_float2(0.f, 0.f);
    for (int gg = 0; gg < NA; ++gg) {
      float v = r[a*NA + gg];
      float2 e = EF[ki*NA + gg];
      acc.x += v*e.x; acc.y += v*e.y;
    }
    xa[idx] = acc;
  }
  __syncthreads();
  size_t obase = ((size_t)beta*ZC + zl)*(NF*NF);
  for (int idx = threadIdx.x; idx < NF*NF; idx += blockDim.x) {
    int mi = idx / NF, ki = idx - mi*NF;
    float2 acc = make_float2(0.f, 0.f);
    for (int a = 0; a < NA; ++a) {
      float2 v = xa[a*NF + ki];
      float2 e = EF[mi*NA + a];
      acc.x += v.x*e.x - v.y*e.y;
      acc.y += v.x*e.y + v.y*e.x;
    }
    Xfp[obase + idx] = acc;
  }
}

// ---- forward Wigner --------------------------------------------------------
__global__ void k8_wigfwd(const float2* __restrict__ XfT,
                          const float* __restrict__ WT,
                          const int4* __restrict__ LMN,
                          float2* __restrict__ XS,
                          int NB, int ZC, int z0, int Ztot) {
  int spec = blockIdx.x;
  int zl = threadIdx.x;
  int4 t = LMN[spec];
  int mi = t.y + 13, ni = t.z + 13;
  float2 acc = make_float2(0.f, 0.f);
  size_t base = (size_t)(mi*27 + ni) * ((size_t)NB*ZC);
  for (int b = 0; b < NB; ++b) {
    float w = WT[(size_t)spec*NB + b];
    float2 v = XfT[base + (size_t)b*ZC + zl];
    acc.x += w*v.x; acc.y += w*v.y;
  }
  XS[(size_t)spec*Ztot + z0 + zl] = acc;
}

// ---- SO3 combine GEMM v3: 8-m-chunk blocks, acc[8] in registers -----------
template<int CI, int CO>
__global__ __launch_bounds__(256)
void k9_gemm3(const float2* __restrict__ XS, const float2* __restrict__ W,
              const int4* __restrict__ tasks, float2* __restrict__ ZSo) {
  constexpr int Zin = 4*CI, Zout = 4*CO;
  constexpr int LOG2CI = (CI==32) ? 5 : (CI==64) ? 6 : 7;
  int4 tk = tasks[blockIdx.x];
  int l = tk.x, m0 = tk.y, c0 = tk.z;
  int L = 2*l + 1;
  int ofs = l*(4*l*l - 1)/3;
  int N = L*CO, K = L*CI;
  __shared__ float2 As[16][33];    // [kk][row], rows = (m-m0)*4 + zb
  __shared__ float2 Bs[16][64];    // [kk][col]
  int t = threadIdx.x;
  int ob = t & 63, kb0 = t >> 6;
  int c = c0 + ob;
  bool colOK = c < N;
  int n = colOK ? c / CO : 0;
  int o = c - n*CO;
  size_t bbase = ((size_t)(ofs + n*L))*(size_t)(CI*CO) + o;
  int q = t >> 6, j = t & 63;
  float2 acc[8];
  #pragma unroll
  for (int u = 0; u < 8; ++u) acc[u] = make_float2(0.f, 0.f);

  for (int k0 = 0; k0 < K; k0 += 16) {
    #pragma unroll
    for (int h = 0; h < 2; ++h) {
      int fi = t + h*256;
      int row = fi >> 4, tc = fi & 15;
      int m = m0 + (row >> 2), zb = row & 3;
      int kk = k0 + tc;
      float2 av = make_float2(0.f, 0.f);
      if (m < L) {
        int kq = kk >> LOG2CI, ii = kk & (CI-1);
        float2 xv = XS[((size_t)(ofs + m*L + kq))*Zin + (size_t)zb*CI + ii];
        av = make_float2(xv.x, -xv.y);
      }
      As[tc][row] = av;
    }
    #pragma unroll
    for (int j2 = 0; j2 < 4; ++j2) {
      int kb = kb0*4 + j2;
      float2 wv = make_float2(0.f, 0.f);
      if (colOK) wv = W[bbase + (size_t)(k0 + kb)*CO];
      Bs[kb][ob] = wv;
    }
    __syncthreads();
    for (int kk2 = 0; kk2 < 16; ++kk2) {
      float2 b = Bs[kk2][j];
      #pragma unroll
      for (int u = 0; u < 8; ++u) {
        float2 a = As[kk2][u*4 + q];
        acc[u].x += a.x*b.x - a.y*b.y;
        acc[u].y += a.x*b.y + a.y*b.x;
      }
    }
    __syncthreads();
  }
  if (colOK) {
    #pragma unroll
    for (int u = 0; u < 8; ++u) {
      int m = m0 + u;
      if (m < L) {
        ZSo[((size_t)(ofs + m*L + n))*Zout + (size_t)q*CO + o] = acc[u];
      }
    }
  }
}

// ---- integrate + FC --------------------------------------------------------
__global__ void k10a_integrate(const float* __restrict__ H5,
                               const float* __restrict__ QW,
                               float* __restrict__ S) {
  int z = blockIdx.x;
  float acc = 0.f;
  for (int idx = threadIdx.x; idx < 28*28*28; idx += blockDim.x) {
    int b = idx / 784;
    acc += H5[(size_t)z*21952 + idx] * QW[b];
  }
  __shared__ float red[256];
  red[threadIdx.x] = acc;
  __syncthreads();
  for (int s = 128; s > 0; s >>= 1) {
    if (threadIdx.x < s) red[threadIdx.x] += red[threadIdx.x + s];
    __syncthreads();
  }
  if (threadIdx.x == 0) S[z] = red[0];
}

__global__ void k10b_fc(const float* __restrict__ S,
                        const float* __restrict__ Wout,
                        const float* __restrict__ bout,
                        float* __restrict__ out) {
  int t = threadIdx.x;
  if (t < 40) {
    int zb = t / 10, c = t % 10;
    float acc = bout[c];
    for (int o = 0; o < 40; ++o) acc += S[zb*40 + o] * Wout[c*40 + o];
    out[zb*10 + c] = acc;
  }
}

// ===========================================================================
// Host side
// ===========================================================================

// upload blob offsets (bytes)
static const size_t U_VT    = 0;                     // 29260 f
static const size_t U_LAM   = 117040;                // 784 f
static const size_t U_QW224 = U_LAM + 3136;          // 224 f
static const size_t U_QW56  = U_QW224 + 896;         // 56 f
static const size_t U_QW28  = U_QW56 + 224;          // 28 f
static const size_t U_TK2   = U_QW28 + 112;          // 1536 int4 each
static const size_t U_TK3   = U_TK2 + 24576;
static const size_t U_TK4   = U_TK3 + 24576;
static const size_t U_TK5   = U_TK4 + 24576;
static const size_t U_BYTES = U_TK5 + 24576;

struct WsOff {
  size_t up, ws2t, wi28t, wf28t, wi14t, wf14t, e224, ef56, ei56, ef28, ei28,
         lmn28, lmn14, idx1, zs1, xsf, zso, HA, HB, S, fixedEnd;
};

static WsOff wsOff() {
  WsOff o; size_t c = 0;
  auto take = [&](size_t bytes) { size_t r = c; c = (c + bytes + 255) & ~(size_t)255; return r; };
  o.up    = take(U_BYTES);
  o.ws2t  = take((size_t)784*224*4);
  o.wi28t = take((size_t)29260*56*4);
  o.wf28t = take((size_t)3654*56*4);
  o.wi14t = take((size_t)3654*28*4);
  o.wf14t = take((size_t)3654*28*4);
  o.e224  = take((size_t)55*224*8);
  o.ef56  = take((size_t)27*56*8);
  o.ei56  = take((size_t)56*55*8);
  o.ef28  = take((size_t)27*28*8);
  o.ei28  = take((size_t)28*27*8);
  o.lmn28 = take((size_t)29260*16);
  o.lmn14 = take((size_t)3654*16);
  o.idx1  = take(784*4);
  o.zs1   = take((size_t)29260*128*8);
  o.xsf   = take((size_t)3654*512*8);
  o.zso   = take((size_t)3654*512*8);
  o.HA    = take((size_t)128*56*56*56*4);
  o.HB    = take((size_t)512*28*28*28*4);
  o.S     = take(1024);
  o.fixedEnd = c;
  return o;
}

// Jacobi eigensolver for symmetric n x n (n <= 55), A destroyed.
static void jacobi_sym(int n, double* A, double* V, double* lam) {
  for (int i = 0; i < n*n; ++i) V[i] = 0.0;
  for (int i = 0; i < n; ++i) V[i*n + i] = 1.0;
  for (int sweep = 0; sweep < 100; ++sweep) {
    double off = 0.0;
    for (int p = 0; p < n; ++p)
      for (int q = p+1; q < n; ++q) off += A[p*n+q]*A[p*n+q];
    if (off < 1e-22) break;
    for (int p = 0; p < n-1; ++p) {
      for (int q = p+1; q < n; ++q) {
        double apq = A[p*n+q];
        if (fabs(apq) < 1e-300) continue;
        double theta = (A[q*n+q] - A[p*n+p]) / (2.0*apq);
        double tt = (theta >= 0 ? 1.0 : -1.0) / (fabs(theta) + sqrt(theta*theta + 1.0));
        double cc = 1.0/sqrt(tt*tt + 1.0), ss = tt*cc;
        for (int i = 0; i < n; ++i) {
          double aip = A[i*n+p], aiq = A[i*n+q];
          A[i*n+p] = cc*aip - ss*aiq;
          A[i*n+q] = ss*aip + cc*aiq;
        }
        for (int i = 0; i < n; ++i) {
          double api = A[p*n+i], aqi = A[q*n+i];
          A[p*n+i] = cc*api - ss*aqi;
          A[q*n+i] = ss*api + cc*aqi;
        }
        for (int i = 0; i < n; ++i) {
          double vip = V[i*n+p], viq = V[i*n+q];
          V[i*n+p] = cc*vip - ss*viq;
          V[i*n+q] = ss*vip + cc*viq;
        }
      }
    }
  }
  for (int i = 0; i < n; ++i) lam[i] = A[i*n+i];
}

extern "C" void kernel_launch(void* const* d_in, const int* in_sizes, int n_in,
                              void* d_out, int out_size, void* d_ws, size_t ws_size,
                              hipStream_t stream) {
  (void)in_sizes; (void)n_in; (void)out_size;
  const WsOff off = wsOff();
  const size_t MINAB = (size_t)3080*32*56*8;      // 44.2 MB: layer-1 T2 chunk
  if (ws_size < off.fixedEnd + 2*MINAB) return;

  const float*  x    = (const float*)d_in[0];
  const float2* w1   = (const float2*)d_in[1];
  const float*  b1   = (const float*)d_in[2];
  const float2* w2   = (const float2*)d_in[3];
  const float*  b2   = (const float*)d_in[4];
  const float2* w3   = (const float2*)d_in[5];
  const float*  b3   = (const float*)d_in[6];
  const float2* w4   = (const float2*)d_in[7];
  const float*  b4   = (const float*)d_in[8];
  const float2* w5   = (const float2*)d_in[9];
  const float*  b5   = (const float*)d_in[10];
  const float*  wout = (const float*)d_in[11];
  const float*  bout = (const float*)d_in[12];
  float* outp = (float*)d_out;
  char* ws = (char*)d_ws;

  // ------------- host: eigen-seeds + quad weights + task tables -----------
  char* hb = new char[U_BYTES];                 // leaked; graph keeps the ptr
  memset(hb, 0, U_BYTES);
  float* hVT  = (float*)(hb + U_VT);
  float* hLAM = (float*)(hb + U_LAM);
  float* hQW224 = (float*)(hb + U_QW224);
  float* hQW56  = (float*)(hb + U_QW56);
  float* hQW28  = (float*)(hb + U_QW28);
  int4*  hTK[4] = {(int4*)(hb + U_TK2), (int4*)(hb + U_TK3),
                   (int4*)(hb + U_TK4), (int4*)(hb + U_TK5)};

  auto quadw = [](int b, double* w) {
    for (int j = 0; j < 2*b; ++j) {
      double s = 0.0;
      for (int k = 0; k < b; ++k)
        s += sin(M_PI*(2*j+1)*(2*k+1)/(4.0*b)) / (double)(2*k+1);
      w[j] = 2.0/b * sin(M_PI*(2*j+1)/(4.0*b)) * s * 2.0*M_PI/((2.0*b)*(2.0*b));
    }
  };
  std::vector<double> qw224(224), qw56(56), qw28v(28);
  quadw(112, qw224.data()); quadw(28, qw56.data()); quadw(14, qw28v.data());
  for (int j = 0; j < 224; ++j) hQW224[j] = (float)qw224[j];
  for (int j = 0; j < 56;  ++j) hQW56[j]  = (float)qw56[j];
  for (int j = 0; j < 28;  ++j) hQW28[j]  = (float)qw28v[j];

  const int NMAX = 55;
  std::vector<double> T(NMAX*NMAX), V(NMAX*NMAX), lam(NMAX);
  for (int l = 0; l < 28; ++l) {
    int n = 2*l + 1;
    std::fill(T.begin(), T.begin() + n*n, 0.0);
    for (int i = 0; i < n-1; ++i) {
      int m = i - l;
      double c = sqrt((double)(l*(l+1)) - (double)(m*(m+1)));
      T[i*n + i + 1] = 0.5*c;
      T[(i+1)*n + i] = 0.5*c;
    }
    jacobi_sym(n, T.data(), V.data(), lam.data());
    size_t vofs = (size_t)l*(4*l*l - 1)/3;
    for (int i = 0; i < n*n; ++i) hVT[vofs + i] = (float)V[i];
    for (int k = 0; k < n; ++k)  hLAM[l*l + k] = (float)lam[k];
  }

  // GEMM task tables (l descending for load balance): (l, m0, c0)
  const int COv[4] = {64, 128, 64, 40};
  int tcnt[4];
  for (int li = 0; li < 4; ++li) {
    int cnt = 0;
    for (int l = 13; l >= 0; --l) {
      int L = 2*l + 1, N = L*COv[li];
      for (int m0 = 0; m0 < L; m0 += 8)
        for (int c0 = 0; c0 < N; c0 += 64)
          hTK[li][cnt++] = make_int4(l, m0, c0, 0);
    }
    tcnt[li] = cnt;   // 560, 1120, 560, 364
  }

  // ------------------- device pointers -------------------
  const float*  dWS2T  = (const float*)(ws + off.ws2t);
  const float*  dWI28T = (const float*)(ws + off.wi28t);
  const float*  dWF28T = (const float*)(ws + off.wf28t);
  const float*  dWI14T = (const float*)(ws + off.wi14t);
  const float*  dWF14T = (const float*)(ws + off.wf14t);
  const float2* dE224  = (const float2*)(ws + off.e224);
  const float2* dEF56  = (const float2*)(ws + off.ef56);
  const float2* dEI56  = (const float2*)(ws + off.ei56);
  const float2* dEF28  = (const float2*)(ws + off.ef28);
  const float2* dEI28  = (const float2*)(ws + off.ei28);
  const int4*   dLMN28 = (const int4*)(ws + off.lmn28);
  const int4*   dLMN14 = (const int4*)(ws + off.lmn14);
  const int*    dIDX1  = (const int*)(ws + off.idx1);
  const float*  dUVT   = (const float*)(ws + off.up + U_VT);
  const float*  dULAM  = (const float*)(ws + off.up + U_LAM);
  const float*  dUQW224= (const float*)(ws + off.up + U_QW224);
  const float*  dUQW56 = (const float*)(ws + off.up + U_QW56);
  const float*  dUQW28 = (const float*)(ws + off.up + U_QW28);
  const int4*   dTK2   = (const int4*)(ws + off.up + U_TK2);
  const int4*   dTK3   = (const int4*)(ws + off.up + U_TK3);
  const int4*   dTK4   = (const int4*)(ws + off.up + U_TK4);
  const int4*   dTK5   = (const int4*)(ws + off.up + U_TK5);
  float2* dZS1 = (float2*)(ws + off.zs1);
  float2* dXSF = (float2*)(ws + off.xsf);
  float2* dZSO = (float2*)(ws + off.zso);
  float*  dHA  = (float*)(ws + off.HA);
  float*  dHB  = (float*)(ws + off.HB);
  float*  dS   = (float*)(ws + off.S);

  size_t ab = ((ws_size - off.fixedEnd)/2) & ~(size_t)255;
  char* Abuf = ws + off.fixedEnd;
  char* Bbuf = Abuf + ab;
  float2* dA = (float2*)Abuf;
  float2* dB = (float2*)Bbuf;
  // xf1/xs1 alias the A buffer (dead before first k4 use of A)
  float2* dXF1 = (float2*)Abuf;                          // 12*224*55 f2
  float2* dXS1 = (float2*)(Abuf + 1182720);              // 784*12 f2

  // ------------------- upload seeds + generate tables -------------------
  hipMemcpyAsync(ws + off.up, hb, U_BYTES, hipMemcpyHostToDevice, stream);
  kg_idx<<<28, 256, 0, stream>>>((int4*)(ws + off.lmn28), (int4*)(ws + off.lmn14),
                                 (int*)(ws + off.idx1));
  kg_tw<<<72, 256, 0, stream>>>((float2*)(ws + off.e224), (float2*)(ws + off.ef56),
                                (float2*)(ws + off.ei56), (float2*)(ws + off.ef28),
                                (float2*)(ws + off.ei28));
  kg_wig<<<784, 224, 0, stream>>>(dUVT, dULAM, dUQW224, nullptr,
                                  (float*)(ws + off.ws2t), 224, 0);
  kg_wig<<<29260, 64, 0, stream>>>(dUVT, dULAM, nullptr, dLMN28,
                                   (float*)(ws + off.wi28t), 56, 1);
  kg_wig<<<3654, 64, 0, stream>>>(dUVT, dULAM, dUQW56, dLMN14,
                                  (float*)(ws + off.wf28t), 56, 2);
  kg_wig<<<3654, 64, 0, stream>>>(dUVT, dULAM, nullptr, dLMN14,
                                  (float*)(ws + off.wi14t), 28, 1);
  kg_wig<<<3654, 64, 0, stream>>>(dUVT, dULAM, dUQW28, dLMN14,
                                  (float*)(ws + off.wf14t), 28, 2);

  // chunk sizes from available A/B space (756/3080 = T2 column counts)
  int zc1 = 32;
  while (zc1 < 128 && (size_t)3080*(size_t)(2*zc1)*56*8 <= ab) zc1 <<= 1;
  auto pick = [&](int Zt)->int {
    int zc = Zt;
    while ((size_t)zc*28*756*8 > ab) zc >>= 1;
    return zc;
  };

  // ------------------- layer 1: s2_conv(112 -> 28) -------------------
  k1_dft_alpha<<<12*224, 64, 0, stream>>>(x, dE224, dXF1);
  k2_s2wig<<<784, 64, 0, stream>>>(dXF1, dWS2T, dIDX1, dXS1);
  k3_combine1<<<29260, 128, 0, stream>>>(dXS1, w1, dLMN28, dZS1);
  for (int z0 = 0; z0 < 128; z0 += zc1) {
    int rowsC = zc1*56;
    k4_wiginv<56,28><<<dim3(3025, zc1/32), 256, 0, stream>>>(dZS1, dWI28T, dA, 128, z0, zc1);
    k5a_idft<55,56><<<dim3(55, 7, (rowsC+255)/256), 256, 0, stream>>>(dA, dEI56, dB, rowsC);
    k5b_idft<55,56><<<dim3(56, (rowsC+15)/16), 256, 0, stream>>>(dB, dEI56, b1, dHA, 56, z0, 32, rowsC);
  }

  // ------------------- layer 2: so3_conv(28 -> 14), 32->64 -----------
  {
    int zc = pick(128);
    for (int z0 = 0; z0 < 128; z0 += zc) {
      k67_dftfwd<56,27><<<zc*56, 256, 0, stream>>>(dHA, dEF56, dB, 56, z0, zc);
      ktr<<<dim3(23, (zc*56+31)/32), dim3(32,8), 0, stream>>>(dB, dA, zc*56, 729);
      k8_wigfwd<<<3654, zc, 0, stream>>>(dA, dWF28T, dLMN14, dXSF, 56, zc, z0, 128);
    }
  }
  k9_gemm3<32,64><<<tcnt[0], 256, 0, stream>>>(dXSF, w2, dTK2, dZSO);
  {
    int zc = pick(256);
    for (int z0 = 0; z0 < 256; z0 += zc) {
      int rowsC = zc*28;
      k4_wiginv<28,14><<<dim3(729, zc/32), 256, 0, stream>>>(dZSO, dWI14T, dA, 256, z0, zc);
      k5a_idft<27,28><<<dim3(27, 4, (rowsC+255)/256), 256, 0, stream>>>(dA, dEI28, dB, rowsC);
      k5b_idft<27,28><<<dim3(28, (rowsC+15)/16), 256, 0, stream>>>(dB, dEI28, b2, dHB, 28, z0, 64, rowsC);
    }
  }

  // ------------------- layer 3: so3_conv(14), 64->128 ----------------
  {
    int zc = pick(256);
    for (int z0 = 0; z0 < 256; z0 += zc) {
      k67_dftfwd<28,27><<<zc*28, 256, 0, stream>>>(dHB, dEF28, dB, 28, z0, zc);
      ktr<<<dim3(23, (zc*28+31)/32), dim3(32,8), 0, stream>>>(dB, dA, zc*28, 729);
      k8_wigfwd<<<3654, zc, 0, stream>>>(dA, dWF14T, dLMN14, dXSF, 28, zc, z0, 256);
    }
  }
  k9_gemm3<64,128><<<tcnt[1], 256, 0, stream>>>(dXSF, w3, dTK3, dZSO);
  {
    int zc = pick(512);
    for (int z0 = 0; z0 < 512; z0 += zc) {
      int rowsC = zc*28;
      k4_wiginv<28,14><<<dim3(729, zc/32), 256, 0, stream>>>(dZSO, dWI14T, dA, 512, z0, zc);
      k5a_idft<27,28><<<dim3(27, 4, (rowsC+255)/256), 256, 0, stream>>>(dA, dEI28, dB, rowsC);
      k5b_idft<27,28><<<dim3(28, (rowsC+15)/16), 256, 0, stream>>>(dB, dEI28, b3, dHA, 28, z0, 128, rowsC);
    }
  }

  // ------------------- layer 4: so3_conv(14), 128->64 ----------------
  {
    int zc = pick(512);
    for (int z0 = 0; z0 < 512; z0 += zc) {
      k67_dftfwd<28,27><<<zc*28, 256, 0, stream>>>(dHA, dEF28, dB, 28, z0, zc);
      ktr<<<dim3(23, (zc*28+31)/32), dim3(32,8), 0, stream>>>(dB, dA, zc*28, 729);
      k8_wigfwd<<<3654, zc, 0, stream>>>(dA, dWF14T, dLMN14, dXSF, 28, zc, z0, 512);
    }
  }
  k9_gemm3<128,64><<<tcnt[2], 256, 0, stream>>>(dXSF, w4, dTK4, dZSO);
  {
    int zc = pick(256);
    for (int z0 = 0; z0 < 256; z0 += zc) {
      int rowsC = zc*28;
      k4_wiginv<28,14><<<dim3(729, zc/32), 256, 0, stream>>>(dZSO, dWI14T, dA, 256, z0, zc);
      k5a_idft<27,28><<<dim3(27, 4, (rowsC+255)/256), 256, 0, stream>>>(dA, dEI28, dB, rowsC);
      k5b_idft<27,28><<<dim3(28, (rowsC+15)/16), 256, 0, stream>>>(dB, dEI28, b4, dHB, 28, z0, 64, rowsC);
    }
  }

  // ------------------- layer 5: so3_conv(14), 64->40 -----------------
  {
    int zc = pick(256);
    for (int z0 = 0; z0 < 256; z0 += zc) {
      k67_dftfwd<28,27><<<zc*28, 256, 0, stream>>>(dHB, dEF28, dB, 28, z0, zc);
      ktr<<<dim3(23, (zc*28+31)/32), dim3(32,8), 0, stream>>>(dB, dA, zc*28, 729);
      k8_wigfwd<<<3654, zc, 0, stream>>>(dA, dWF14T, dLMN14, dXSF, 28, zc, z0, 256);
    }
  }
  k9_gemm3<64,40><<<tcnt[3], 256, 0, stream>>>(dXSF, w5, dTK5, dZSO);
  {
    // Z = 160 fits in one chunk (T2 = 27 MB <= ab)
    int rowsC = 160*28;
    k4_wiginv<28,14><<<dim3(729, 5), 256, 0, stream>>>(dZSO, dWI14T, dA, 160, 0, 160);
    k5a_idft<27,28><<<dim3(27, 4, (rowsC+255)/256), 256, 0, stream>>>(dA, dEI28, dB, rowsC);
    k5b_idft<27,28><<<dim3(28, (rowsC+15)/16), 256, 0, stream>>>(dB, dEI28, b5, dHA, 28, 0, 40, rowsC);
  }

  // ------------------- integrate + FC -------------------
  k10a_integrate<<<160, 256, 0, stream>>>(dHA, dUQW28, dS);
  k10b_fc<<<1, 64, 0, stream>>>(dS, wout, bout, outp);
}

// Round 9
// 4336.050 us; speedup vs baseline: 1.2065x; 1.2065x over previous
//
#include <hip/hip_runtime.h>
#include <cmath>
#include <cstring>
#include <vector>

// ---------------------------------------------------------------------------
// S2ConvNet forward. Round 9:
//  - spatial domain stored transposed: Ht[(a,g)][b*Ztot+z]  (row-last)
//  - forward 2D DFT = kf1/kf2 GEMM-shaped kernels (k67 + ktr deleted);
//    output lands directly in k8's layout
//  - k4 writes beta-major rows; k5b loop-swapped, writes Ht transposed
//  - gemm task tables c0-major (m0 siblings adjacent -> L2 B reuse)
// ---------------------------------------------------------------------------

// ======================= table-generation kernels ==========================

__global__ void kg_idx(int4* __restrict__ LMN28, int4* __restrict__ LMN14,
                       int* __restrict__ IDX1) {
  int l = blockIdx.x;                 // 0..27
  int L = 2*l + 1, ofs = l*(4*l*l - 1)/3;
  for (int i = threadIdx.x; i < L*L; i += blockDim.x) {
    int a = i / L, c = i - a*L;
    int4 v = make_int4(l, a - l, c - l, 0);
    LMN28[ofs + i] = v;
    if (l < 14) LMN14[ofs + i] = v;
  }
  for (int a = threadIdx.x; a < L; a += blockDim.x)
    IDX1[l*l + a] = (a - l) + 27;
}

__global__ void kg_tw(float2* __restrict__ E224, float2* __restrict__ EF56,
                      float2* __restrict__ EI56, float2* __restrict__ EF28,
                      float2* __restrict__ EI28) {
  int t = blockIdx.x*256 + threadIdx.x;
  const float TP = 6.283185307179586f;
  if (t < 12320) {                      // E224: 55 x 224, fwd
    int mi = t/224, a = t - mi*224;
    int r = ((mi - 27)*a) % 224;
    float ang = -TP*r/224.f;
    E224[t] = make_float2(cosf(ang), sinf(ang)); return;
  }
  t -= 12320;
  if (t < 1512) {                       // EF56: 27 x 56, fwd
    int ki = t/56, g = t - ki*56;
    int r = ((ki - 13)*g) % 56;
    float ang = -TP*r/56.f;
    EF56[t] = make_float2(cosf(ang), sinf(ang)); return;
  }
  t -= 1512;
  if (t < 3080) {                       // EI56: 56 x 55, inv
    int a = t/55, mi = t - a*55;
    int r = ((mi - 27)*a) % 56;
    float ang = TP*r/56.f;
    EI56[t] = make_float2(cosf(ang), sinf(ang)); return;
  }
  t -= 3080;
  if (t < 756) {                        // EF28: 27 x 28, fwd
    int ki = t/28, g = t - ki*28;
    int r = ((ki - 13)*g) % 28;
    float ang = -TP*r/28.f;
    EF28[t] = make_float2(cosf(ang), sinf(ang)); return;
  }
  t -= 756;
  if (t < 756) {                        // EI28: 28 x 27, inv
    int a = t/27, mi = t - a*27;
    int r = ((mi - 13)*a) % 28;
    float ang = TP*r/28.f;
    EI28[t] = make_float2(cosf(ang), sinf(ang));
  }
}

// Wigner-d tables from eigen-seed
__global__ void kg_wig(const float* __restrict__ VT, const float* __restrict__ LAM,
                       const float* __restrict__ QW, const int4* __restrict__ LMN,
                       float* __restrict__ OUT, int NB, int mode) {
  int spec = blockIdx.x;
  int l, a, c;
  if (mode == 0) {
    l = 0; while ((l+1)*(l+1) <= spec) ++l;
    a = spec - l*l; c = l;
  } else {
    int4 t4 = LMN[spec];
    l = t4.x; a = t4.y + l; c = t4.z + l;
  }
  int n = 2*l + 1;
  const float* V = VT + (size_t)l*(4*l*l - 1)/3;
  const float* lam = LAM + l*l;
  int j = threadIdx.x;
  if (j >= NB) return;
  float be = (j + 0.5f)*(float)M_PI/NB;
  float sc = 0.f, ss = 0.f;
  for (int k = 0; k < n; ++k) {
    float vv = V[a*n + k]*V[c*n + k];
    float x = be*lam[k];
    sc += vv*cosf(x); ss += vv*sinf(x);
  }
  int p = (a - c) & 3;
  float dv = (p==0) ? sc : (p==1) ? -ss : (p==2) ? -sc : ss;
  float w = (mode == 1) ? (float)n : QW[j];
  OUT[(size_t)spec*NB + j] = w*dv;
}

// ============================ pipeline kernels =============================

// ---- Stage 1a: DFT over alpha (224 -> 55 freqs), real input --------------
__global__ void k1_dft_alpha(const float* __restrict__ x,
                             const float2* __restrict__ E,
                             float2* __restrict__ XF) {
  int row = blockIdx.x;                       // z*224 + beta
  __shared__ float r[224];
  for (int i = threadIdx.x; i < 224; i += 64) r[i] = x[(size_t)row*224 + i];
  __syncthreads();
  int mi = threadIdx.x;
  if (mi < 55) {
    float2 acc = make_float2(0.f, 0.f);
    for (int a = 0; a < 224; ++a) {
      float v = r[a];
      float2 e = E[mi*224 + a];
      acc.x += v*e.x; acc.y += v*e.y;
    }
    XF[(size_t)row*55 + mi] = acc;
  }
}

// ---- Stage 1b: S2 Wigner contraction over beta ---------------------------
__global__ void k2_s2wig(const float2* __restrict__ XF,
                         const float* __restrict__ W,
                         const int* __restrict__ IDX,
                         float2* __restrict__ XS) {
  int lm = blockIdx.x;
  int z = threadIdx.x;
  if (z >= 12) return;
  int mi = IDX[lm];
  float2 acc = make_float2(0.f, 0.f);
  for (int b = 0; b < 224; ++b) {
    float w = W[(size_t)lm*224 + b];
    float2 v = XF[((size_t)z*224 + b)*55 + mi];
    acc.x += w*v.x; acc.y += w*v.y;
  }
  XS[lm*12 + z] = acc;
}

// ---- Layer-1 combine ------------------------------------------------------
__global__ void k3_combine1(const float2* __restrict__ XS,
                            const float2* __restrict__ W1,
                            const int4* __restrict__ LMN,
                            float2* __restrict__ ZS) {
  int r = blockIdx.x;
  int4 t = LMN[r];
  int l = t.x, m = t.y, n = t.z;
  int sm = l*l + l + m, sn = l*l + l + n;
  int zb = threadIdx.x >> 5, o = threadIdx.x & 31;
  float2 acc = make_float2(0.f, 0.f);
  #pragma unroll
  for (int i = 0; i < 3; ++i) {
    float2 xv = XS[sm*12 + zb*3 + i];
    float2 wv = W1[(sn*3 + i)*32 + o];
    acc.x += xv.x*wv.x + xv.y*wv.y;   // xv * conj(wv)
    acc.y += xv.y*wv.x - xv.x*wv.y;
  }
  ZS[(size_t)r*128 + threadIdx.x] = acc;
}

// ---- Inverse Wigner: Gp[(mi,ni)][b*ZC+zl] ---------------------------------
template<int NB, int NL>
__global__ void k4_wiginv(const float2* __restrict__ ZS,
                          const float* __restrict__ WT,
                          float2* __restrict__ Gp,
                          int Ztot, int z0, int ZC) {
  constexpr int NF = 2*NL - 1;
  constexpr int NJ = (NB + 7)/8;
  int bx = blockIdx.x;
  int mi = bx / NF, ni = bx % NF;
  int m = mi - (NL-1), n = ni - (NL-1);
  int zl = blockIdx.y*32 + (threadIdx.x & 31);
  int g  = threadIdx.x >> 5;     // 0..7
  float2 acc[NJ];
  #pragma unroll
  for (int j = 0; j < NJ; ++j) acc[j] = make_float2(0.f, 0.f);
  int am = m < 0 ? -m : m, an = n < 0 ? -n : n;
  int lmin = am > an ? am : an;
  for (int l = lmin; l < NL; ++l) {
    int L = 2*l + 1;
    int spec = l*(4*l*l - 1)/3 + (m + l)*L + (n + l);
    float2 zv = ZS[(size_t)spec*Ztot + z0 + zl];
    #pragma unroll
    for (int j = 0; j < NJ; ++j) {
      int b = g + j*8;
      if (b < NB) {
        float w = WT[(size_t)spec*NB + b];
        acc[j].x += w*zv.x; acc[j].y += w*zv.y;
      }
    }
  }
  size_t base = (size_t)bx * ((size_t)ZC*NB) + zl;
  #pragma unroll
  for (int j = 0; j < NJ; ++j) {
    int b = g + j*8;
    if (b < NB) Gp[base + (size_t)b*ZC] = acc[j];
  }
}

// ---- idft stage A: contract mi. T2[(a,ni)][row] = sum_mi EI[a,mi]*G[(mi,ni)][row]
template<int NF, int NA>
__global__ __launch_bounds__(256)
void k5a_idft(const float2* __restrict__ G, const float2* __restrict__ EI,
              float2* __restrict__ T2, int rowsC) {
  int ni = blockIdx.x;
  int at = blockIdx.y;
  int row = blockIdx.z*256 + threadIdx.x;
  if (row >= rowsC) return;
  float2 acc[8];
  #pragma unroll
  for (int u = 0; u < 8; ++u) acc[u] = make_float2(0.f, 0.f);
  const float2* gp = G + (size_t)ni*rowsC + row;
  for (int mi = 0; mi < NF; ++mi) {
    float2 gv = gp[(size_t)mi*NF*rowsC];
    #pragma unroll
    for (int u = 0; u < 8; ++u) {
      int a = at*8 + u; if (a >= NA) a = NA-1;       // clamp (result discarded)
      float2 e = EI[a*NF + mi];                      // block-uniform -> s_load
      acc[u].x += e.x*gv.x - e.y*gv.y;
      acc[u].y += e.x*gv.y + e.y*gv.x;
    }
  }
  #pragma unroll
  for (int u = 0; u < 8; ++u) {
    int a = at*8 + u;
    if (a < NA) T2[((size_t)a*NF + ni)*rowsC + row] = acc[u];
  }
}

// ---- idft stage B: contract ni, Re + bias + relu, write Ht[(a,g)][b*Zt+z] --
template<int NF, int NA>
__global__ __launch_bounds__(256)
void k5b_idft(const float2* __restrict__ T2, const float2* __restrict__ EI,
              const float* __restrict__ bias, float* __restrict__ Ht,
              int ZC, int z0, int Zt, int NB, int Cout, int rowsC) {
  constexpr int NAIT = NA/4;
  __shared__ float2 EIs[NA*NF];
  __shared__ float2 Ts[NF][64];
  int a = blockIdx.x;
  int row0 = blockIdx.y*64;
  int t = threadIdx.x;
  for (int i = t; i < NA*NF; i += 256) EIs[i] = EI[i];
  for (int i = t; i < NF*64; i += 256) {
    int ni = i >> 6, rr = i & 63;
    int row = row0 + rr;
    Ts[ni][rr] = (row < rowsC) ? T2[((size_t)a*NF + ni)*rowsC + row]
                               : make_float2(0.f, 0.f);
  }
  __syncthreads();
  int r = t & 63, gq = t >> 6;
  int row = row0 + r;
  if (row >= rowsC) return;
  int b = row / ZC, zl = row - b*ZC;
  int z = z0 + zl;
  float bv = bias[z % Cout];
  float facc[NAIT];
  #pragma unroll
  for (int it = 0; it < NAIT; ++it) facc[it] = 0.f;
  for (int ni = 0; ni < NF; ++ni) {
    float2 tv = Ts[ni][r];
    #pragma unroll
    for (int it = 0; it < NAIT; ++it) {
      float2 e = EIs[(gq + 4*it)*NF + ni];     // wave-uniform -> broadcast
      facc[it] += e.x*tv.x - e.y*tv.y;
    }
  }
  size_t hb = (size_t)(a*NA)*(size_t)(NB*Zt) + (size_t)b*Zt + z;
  #pragma unroll
  for (int it = 0; it < NAIT; ++it) {
    int g = gq + 4*it;
    Ht[hb + (size_t)g*(NB*Zt)] = fmaxf(facc[it] + bv, 0.f);
  }
}

// ---- fwd DFT stage 1: contract g. XA[(a,ki)][row] = sum_g Ht*EF[ki][g] ----
template<int NA, int NF>
__global__ __launch_bounds__(256)
void kf1_dftg(const float* __restrict__ Ht, const float2* __restrict__ EF,
              float2* __restrict__ XA, int NB, int Zt, int z0, int ZC, int rowsC) {
  int a = blockIdx.x;
  int kt = blockIdx.y;                 // 0..1 (14 freqs each)
  int row = blockIdx.z*256 + threadIdx.x;
  if (row >= rowsC) return;
  int b = row / ZC, zl = row - b*ZC;
  size_t hbase = (size_t)(a*NA)*(size_t)(NB*Zt) + (size_t)b*Zt + z0 + zl;
  float2 acc[14];
  #pragma unroll
  for (int u = 0; u < 14; ++u) acc[u] = make_float2(0.f, 0.f);
  for (int g = 0; g < NA; ++g) {
    float hv = Ht[hbase + (size_t)g*(NB*Zt)];
    #pragma unroll
    for (int u = 0; u < 14; ++u) {
      int ki = kt*14 + u; if (ki >= NF) ki = NF-1;
      float2 e = EF[ki*NA + g];               // block-uniform -> s_load
      acc[u].x += hv*e.x; acc[u].y += hv*e.y;
    }
  }
  #pragma unroll
  for (int u = 0; u < 14; ++u) {
    int ki = kt*14 + u;
    if (ki < NF) XA[((size_t)a*NF + ki)*rowsC + row] = acc[u];
  }
}

// ---- fwd DFT stage 2: contract a. Xf[(mi,ki)][row] = sum_a XA*EF[mi][a] ---
template<int NA, int NF>
__global__ __launch_bounds__(256)
void kf2_dfta(const float2* __restrict__ XA, const float2* __restrict__ EF,
              float2* __restrict__ Xf, int rowsC) {
  int ki = blockIdx.x;                 // 0..NF-1
  int mt = blockIdx.y;                 // 0..1
  int row = blockIdx.z*256 + threadIdx.x;
  if (row >= rowsC) return;
  float2 acc[14];
  #pragma unroll
  for (int u = 0; u < 14; ++u) acc[u] = make_float2(0.f, 0.f);
  const float2* xp = XA + (size_t)ki*rowsC + row;
  for (int a = 0; a < NA; ++a) {
    float2 v = xp[(size_t)a*NF*rowsC];
    #pragma unroll
    for (int u = 0; u < 14; ++u) {
      int mi = mt*14 + u; if (mi >= NF) mi = NF-1;
      float2 e = EF[mi*NA + a];
      acc[u].x += v.x*e.x - v.y*e.y;
      acc[u].y += v.x*e.y + v.y*e.x;
    }
  }
  #pragma unroll
  for (int u = 0; u < 14; ++u) {
    int mi = mt*14 + u;
    if (mi < NF) Xf[((size_t)mi*NF + ki)*rowsC + row] = acc[u];
  }
}

// ---- forward Wigner --------------------------------------------------------
__global__ void k8_wigfwd(const float2* __restrict__ XfT,
                          const float* __restrict__ WT,
                          const int4* __restrict__ LMN,
                          float2* __restrict__ XS,
                          int NB, int ZC, int z0, int Ztot) {
  int spec = blockIdx.x;
  int zl = threadIdx.x;
  int4 t = LMN[spec];
  int mi = t.y + 13, ni = t.z + 13;
  float2 acc = make_float2(0.f, 0.f);
  size_t base = (size_t)(mi*27 + ni) * ((size_t)NB*ZC);
  for (int b = 0; b < NB; ++b) {
    float w = WT[(size_t)spec*NB + b];
    float2 v = XfT[base + (size_t)b*ZC + zl];
    acc.x += w*v.x; acc.y += w*v.y;
  }
  XS[(size_t)spec*Ztot + z0 + zl] = acc;
}

// ---- SO3 combine GEMM v3: 8-m-chunk blocks, acc[8] in registers -----------
template<int CI, int CO>
__global__ __launch_bounds__(256)
void k9_gemm3(const float2* __restrict__ XS, const float2* __restrict__ W,
              const int4* __restrict__ tasks, float2* __restrict__ ZSo) {
  constexpr int Zin = 4*CI, Zout = 4*CO;
  constexpr int LOG2CI = (CI==32) ? 5 : (CI==64) ? 6 : 7;
  int4 tk = tasks[blockIdx.x];
  int l = tk.x, m0 = tk.y, c0 = tk.z;
  int L = 2*l + 1;
  int ofs = l*(4*l*l - 1)/3;
  int N = L*CO, K = L*CI;
  __shared__ float2 As[16][33];    // [kk][row], rows = (m-m0)*4 + zb
  __shared__ float2 Bs[16][64];    // [kk][col]
  int t = threadIdx.x;
  int ob = t & 63, kb0 = t >> 6;
  int c = c0 + ob;
  bool colOK = c < N;
  int n = colOK ? c / CO : 0;
  int o = c - n*CO;
  size_t bbase = ((size_t)(ofs + n*L))*(size_t)(CI*CO) + o;
  int q = t >> 6, j = t & 63;
  float2 acc[8];
  #pragma unroll
  for (int u = 0; u < 8; ++u) acc[u] = make_float2(0.f, 0.f);

  for (int k0 = 0; k0 < K; k0 += 16) {
    #pragma unroll
    for (int h = 0; h < 2; ++h) {
      int fi = t + h*256;
      int row = fi >> 4, tc = fi & 15;
      int m = m0 + (row >> 2), zb = row & 3;
      int kk = k0 + tc;
      float2 av = make_float2(0.f, 0.f);
      if (m < L) {
        int kq = kk >> LOG2CI, ii = kk & (CI-1);
        float2 xv = XS[((size_t)(ofs + m*L + kq))*Zin + (size_t)zb*CI + ii];
        av = make_float2(xv.x, -xv.y);
      }
      As[tc][row] = av;
    }
    #pragma unroll
    for (int j2 = 0; j2 < 4; ++j2) {
      int kb = kb0*4 + j2;
      float2 wv = make_float2(0.f, 0.f);
      if (colOK) wv = W[bbase + (size_t)(k0 + kb)*CO];
      Bs[kb][ob] = wv;
    }
    __syncthreads();
    for (int kk2 = 0; kk2 < 16; ++kk2) {
      float2 b = Bs[kk2][j];
      #pragma unroll
      for (int u = 0; u < 8; ++u) {
        float2 a = As[kk2][u*4 + q];
        acc[u].x += a.x*b.x - a.y*b.y;
        acc[u].y += a.x*b.y + a.y*b.x;
      }
    }
    __syncthreads();
  }
  if (colOK) {
    #pragma unroll
    for (int u = 0; u < 8; ++u) {
      int m = m0 + u;
      if (m < L) {
        ZSo[((size_t)(ofs + m*L + n))*Zout + (size_t)q*CO + o] = acc[u];
      }
    }
  }
}

// ---- integrate (new Ht layout) + FC ---------------------------------------
// Cpart[p][col] = partial column sums of Ht (rows = (a,g), cols = b*Zt+z)
__global__ void k10a_colsum(const float* __restrict__ Ht, float* __restrict__ Cp,
                            int rows, int cols, int rowsPer) {
  int col = blockIdx.x*256 + threadIdx.x;
  if (col >= cols) return;
  int r0 = blockIdx.y*rowsPer;
  int r1 = r0 + rowsPer; if (r1 > rows) r1 = rows;
  float acc = 0.f;
  for (int r = r0; r < r1; ++r) acc += Ht[(size_t)r*cols + col];
  Cp[(size_t)blockIdx.y*cols + col] = acc;
}

__global__ void k10a_fin(const float* __restrict__ Cp, const float* __restrict__ QW,
                         float* __restrict__ S, int Zt, int NB, int nparts) {
  int z = blockIdx.x*64 + threadIdx.x;
  if (z >= Zt) return;
  int cols = NB*Zt;
  float acc = 0.f;
  for (int b = 0; b < NB; ++b) {
    float cs = 0.f;
    for (int p = 0; p < nparts; ++p) cs += Cp[(size_t)p*cols + b*Zt + z];
    acc += cs * QW[b];
  }
  S[z] = acc;
}

__global__ void k10b_fc(const float* __restrict__ S,
                        const float* __restrict__ Wout,
                        const float* __restrict__ bout,
                        float* __restrict__ out) {
  int t = threadIdx.x;
  if (t < 40) {
    int zb = t / 10, c = t % 10;
    float acc = bout[c];
    for (int o = 0; o < 40; ++o) acc += S[zb*40 + o] * Wout[c*40 + o];
    out[zb*10 + c] = acc;
  }
}

// ===========================================================================
// Host side
// ===========================================================================

// upload blob offsets (bytes)
static const size_t U_VT    = 0;                     // 29260 f
static const size_t U_LAM   = 117040;                // 784 f
static const size_t U_QW224 = U_LAM + 3136;          // 224 f
static const size_t U_QW56  = U_QW224 + 896;         // 56 f
static const size_t U_QW28  = U_QW56 + 224;          // 28 f
static const size_t U_TK2   = U_QW28 + 112;          // 1536 int4 each
static const size_t U_TK3   = U_TK2 + 24576;
static const size_t U_TK4   = U_TK3 + 24576;
static const size_t U_TK5   = U_TK4 + 24576;
static const size_t U_BYTES = U_TK5 + 24576;

struct WsOff {
  size_t up, ws2t, wi28t, wf28t, wi14t, wf14t, e224, ef56, ei56, ef28, ei28,
         lmn28, lmn14, idx1, zs1, xsf, zso, HA, HB, S, fixedEnd;
};

static WsOff wsOff() {
  WsOff o; size_t c = 0;
  auto take = [&](size_t bytes) { size_t r = c; c = (c + bytes + 255) & ~(size_t)255; return r; };
  o.up    = take(U_BYTES);
  o.ws2t  = take((size_t)784*224*4);
  o.wi28t = take((size_t)29260*56*4);
  o.wf28t = take((size_t)3654*56*4);
  o.wi14t = take((size_t)3654*28*4);
  o.wf14t = take((size_t)3654*28*4);
  o.e224  = take((size_t)55*224*8);
  o.ef56  = take((size_t)27*56*8);
  o.ei56  = take((size_t)56*55*8);
  o.ef28  = take((size_t)27*28*8);
  o.ei28  = take((size_t)28*27*8);
  o.lmn28 = take((size_t)29260*16);
  o.lmn14 = take((size_t)3654*16);
  o.idx1  = take(784*4);
  o.zs1   = take((size_t)29260*128*8);
  o.xsf   = take((size_t)3654*512*8);
  o.zso   = take((size_t)3654*512*8);
  o.HA    = take((size_t)128*56*56*56*4);
  o.HB    = take((size_t)512*28*28*28*4);
  o.S     = take(16*4480*4 + 1024);
  o.fixedEnd = c;
  return o;
}

// Jacobi eigensolver for symmetric n x n (n <= 55), A destroyed.
static void jacobi_sym(int n, double* A, double* V, double* lam) {
  for (int i = 0; i < n*n; ++i) V[i] = 0.0;
  for (int i = 0; i < n; ++i) V[i*n + i] = 1.0;
  for (int sweep = 0; sweep < 100; ++sweep) {
    double off = 0.0;
    for (int p = 0; p < n; ++p)
      for (int q = p+1; q < n; ++q) off += A[p*n+q]*A[p*n+q];
    if (off < 1e-22) break;
    for (int p = 0; p < n-1; ++p) {
      for (int q = p+1; q < n; ++q) {
        double apq = A[p*n+q];
        if (fabs(apq) < 1e-300) continue;
        double theta = (A[q*n+q] - A[p*n+p]) / (2.0*apq);
        double tt = (theta >= 0 ? 1.0 : -1.0) / (fabs(theta) + sqrt(theta*theta + 1.0));
        double cc = 1.0/sqrt(tt*tt + 1.0), ss = tt*cc;
        for (int i = 0; i < n; ++i) {
          double aip = A[i*n+p], aiq = A[i*n+q];
          A[i*n+p] = cc*aip - ss*aiq;
          A[i*n+q] = ss*aip + cc*aiq;
        }
        for (int i = 0; i < n; ++i) {
          double api = A[p*n+i], aqi = A[q*n+i];
          A[p*n+i] = cc*api - ss*aqi;
          A[q*n+i] = ss*api + cc*aqi;
        }
        for (int i = 0; i < n; ++i) {
          double vip = V[i*n+p], viq = V[i*n+q];
          V[i*n+p] = cc*vip - ss*viq;
          V[i*n+q] = ss*vip + cc*viq;
        }
      }
    }
  }
  for (int i = 0; i < n; ++i) lam[i] = A[i*n+i];
}

extern "C" void kernel_launch(void* const* d_in, const int* in_sizes, int n_in,
                              void* d_out, int out_size, void* d_ws, size_t ws_size,
                              hipStream_t stream) {
  (void)in_sizes; (void)n_in; (void)out_size;
  const WsOff off = wsOff();
  const size_t MINAB = (size_t)3080*32*56*8;      // 44.2 MB: layer-1 T2 chunk
  if (ws_size < off.fixedEnd + 2*MINAB) return;

  const float*  x    = (const float*)d_in[0];
  const float2* w1   = (const float2*)d_in[1];
  const float*  b1   = (const float*)d_in[2];
  const float2* w2   = (const float2*)d_in[3];
  const float*  b2   = (const float*)d_in[4];
  const float2* w3   = (const float2*)d_in[5];
  const float*  b3   = (const float*)d_in[6];
  const float2* w4   = (const float2*)d_in[7];
  const float*  b4   = (const float*)d_in[8];
  const float2* w5   = (const float2*)d_in[9];
  const float*  b5   = (const float*)d_in[10];
  const float*  wout = (const float*)d_in[11];
  const float*  bout = (const float*)d_in[12];
  float* outp = (float*)d_out;
  char* ws = (char*)d_ws;

  // ------------- host: eigen-seeds + quad weights + task tables -----------
  char* hb = new char[U_BYTES];                 // leaked; graph keeps the ptr
  memset(hb, 0, U_BYTES);
  float* hVT  = (float*)(hb + U_VT);
  float* hLAM = (float*)(hb + U_LAM);
  float* hQW224 = (float*)(hb + U_QW224);
  float* hQW56  = (float*)(hb + U_QW56);
  float* hQW28  = (float*)(hb + U_QW28);
  int4*  hTK[4] = {(int4*)(hb + U_TK2), (int4*)(hb + U_TK3),
                   (int4*)(hb + U_TK4), (int4*)(hb + U_TK5)};

  auto quadw = [](int b, double* w) {
    for (int j = 0; j < 2*b; ++j) {
      double s = 0.0;
      for (int k = 0; k < b; ++k)
        s += sin(M_PI*(2*j+1)*(2*k+1)/(4.0*b)) / (double)(2*k+1);
      w[j] = 2.0/b * sin(M_PI*(2*j+1)/(4.0*b)) * s * 2.0*M_PI/((2.0*b)*(2.0*b));
    }
  };
  std::vector<double> qw224(224), qw56(56), qw28v(28);
  quadw(112, qw224.data()); quadw(28, qw56.data()); quadw(14, qw28v.data());
  for (int j = 0; j < 224; ++j) hQW224[j] = (float)qw224[j];
  for (int j = 0; j < 56;  ++j) hQW56[j]  = (float)qw56[j];
  for (int j = 0; j < 28;  ++j) hQW28[j]  = (float)qw28v[j];

  const int NMAX = 55;
  std::vector<double> T(NMAX*NMAX), V(NMAX*NMAX), lam(NMAX);
  for (int l = 0; l < 28; ++l) {
    int n = 2*l + 1;
    std::fill(T.begin(), T.begin() + n*n, 0.0);
    for (int i = 0; i < n-1; ++i) {
      int m = i - l;
      double c = sqrt((double)(l*(l+1)) - (double)(m*(m+1)));
      T[i*n + i + 1] = 0.5*c;
      T[(i+1)*n + i] = 0.5*c;
    }
    jacobi_sym(n, T.data(), V.data(), lam.data());
    size_t vofs = (size_t)l*(4*l*l - 1)/3;
    for (int i = 0; i < n*n; ++i) hVT[vofs + i] = (float)V[i];
    for (int k = 0; k < n; ++k)  hLAM[l*l + k] = (float)lam[k];
  }

  // GEMM task tables: l descending, c0-major (m0 siblings adjacent -> L2 reuse)
  const int COv[4] = {64, 128, 64, 40};
  int tcnt[4];
  for (int li = 0; li < 4; ++li) {
    int cnt = 0;
    for (int l = 13; l >= 0; --l) {
      int L = 2*l + 1, N = L*COv[li];
      for (int c0 = 0; c0 < N; c0 += 64)
        for (int m0 = 0; m0 < L; m0 += 8)
          hTK[li][cnt++] = make_int4(l, m0, c0, 0);
    }
    tcnt[li] = cnt;   // 560, 1120, 560, 364
  }

  // ------------------- device pointers -------------------
  const float*  dWS2T  = (const float*)(ws + off.ws2t);
  const float*  dWI28T = (const float*)(ws + off.wi28t);
  const float*  dWF28T = (const float*)(ws + off.wf28t);
  const float*  dWI14T = (const float*)(ws + off.wi14t);
  const float*  dWF14T = (const float*)(ws + off.wf14t);
  const float2* dE224  = (const float2*)(ws + off.e224);
  const float2* dEF56  = (const float2*)(ws + off.ef56);
  const float2* dEI56  = (const float2*)(ws + off.ei56);
  const float2* dEF28  = (const float2*)(ws + off.ef28);
  const float2* dEI28  = (const float2*)(ws + off.ei28);
  const int4*   dLMN28 = (const int4*)(ws + off.lmn28);
  const int4*   dLMN14 = (const int4*)(ws + off.lmn14);
  const int*    dIDX1  = (const int*)(ws + off.idx1);
  const float*  dUVT   = (const float*)(ws + off.up + U_VT);
  const float*  dULAM  = (const float*)(ws + off.up + U_LAM);
  const float*  dUQW224= (const float*)(ws + off.up + U_QW224);
  const float*  dUQW56 = (const float*)(ws + off.up + U_QW56);
  const float*  dUQW28 = (const float*)(ws + off.up + U_QW28);
  const int4*   dTK2   = (const int4*)(ws + off.up + U_TK2);
  const int4*   dTK3   = (const int4*)(ws + off.up + U_TK3);
  const int4*   dTK4   = (const int4*)(ws + off.up + U_TK4);
  const int4*   dTK5   = (const int4*)(ws + off.up + U_TK5);
  float2* dZS1 = (float2*)(ws + off.zs1);
  float2* dXSF = (float2*)(ws + off.xsf);
  float2* dZSO = (float2*)(ws + off.zso);
  float*  dHA  = (float*)(ws + off.HA);
  float*  dHB  = (float*)(ws + off.HB);
  float*  dCp  = (float*)(ws + off.S);                  // 16 x 4480 partials
  float*  dS   = (float*)(ws + off.S + 16*4480*4);      // 160 sums

  size_t ab = ((ws_size - off.fixedEnd)/2) & ~(size_t)255;
  char* Abuf = ws + off.fixedEnd;
  char* Bbuf = Abuf + ab;
  float2* dA = (float2*)Abuf;
  float2* dB = (float2*)Bbuf;
  // xf1/xs1 alias the A buffer (dead before first k4 use of A)
  float2* dXF1 = (float2*)Abuf;                          // 12*224*55 f2
  float2* dXS1 = (float2*)(Abuf + 1182720);              // 784*12 f2

  // ------------------- upload seeds + generate tables -------------------
  hipMemcpyAsync(ws + off.up, hb, U_BYTES, hipMemcpyHostToDevice, stream);
  kg_idx<<<28, 256, 0, stream>>>((int4*)(ws + off.lmn28), (int4*)(ws + off.lmn14),
                                 (int*)(ws + off.idx1));
  kg_tw<<<72, 256, 0, stream>>>((float2*)(ws + off.e224), (float2*)(ws + off.ef56),
                                (float2*)(ws + off.ei56), (float2*)(ws + off.ef28),
                                (float2*)(ws + off.ei28));
  kg_wig<<<784, 224, 0, stream>>>(dUVT, dULAM, dUQW224, nullptr,
                                  (float*)(ws + off.ws2t), 224, 0);
  kg_wig<<<29260, 64, 0, stream>>>(dUVT, dULAM, nullptr, dLMN28,
                                   (float*)(ws + off.wi28t), 56, 1);
  kg_wig<<<3654, 64, 0, stream>>>(dUVT, dULAM, dUQW56, dLMN14,
                                  (float*)(ws + off.wf28t), 56, 2);
  kg_wig<<<3654, 64, 0, stream>>>(dUVT, dULAM, nullptr, dLMN14,
                                  (float*)(ws + off.wi14t), 28, 1);
  kg_wig<<<3654, 64, 0, stream>>>(dUVT, dULAM, dUQW28, dLMN14,
                                  (float*)(ws + off.wf14t), 28, 2);

  // chunk pickers (bytes-per-z of the largest chunk buffer)
  auto pickPow2 = [&](int Zt, size_t perz)->int {
    int zc = Zt;
    while (zc > 32 && perz*(size_t)zc > ab) zc >>= 1;
    return zc;
  };
  int zc1  = pickPow2(128, (size_t)3080*56*8);   // layer-1 inverse (T2 biggest)
  int zcF2 = pickPow2(128, (size_t)56*27*56*8);  // layer-2 fwd (XA biggest)
  int zcI  = pickPow2(256, (size_t)756*28*8);    // b=14 inverse
  int zcF  = pickPow2(256, (size_t)28*27*28*8);  // b=14 fwd (Zt<=512 chunks)

  // ------------------- layer 1: s2_conv(112 -> 28) -------------------
  k1_dft_alpha<<<12*224, 64, 0, stream>>>(x, dE224, dXF1);
  k2_s2wig<<<784, 64, 0, stream>>>(dXF1, dWS2T, dIDX1, dXS1);
  k3_combine1<<<29260, 128, 0, stream>>>(dXS1, w1, dLMN28, dZS1);
  for (int z0 = 0; z0 < 128; z0 += zc1) {
    int rowsC = zc1*56;
    k4_wiginv<56,28><<<dim3(3025, zc1/32), 256, 0, stream>>>(dZS1, dWI28T, dA, 128, z0, zc1);
    k5a_idft<55,56><<<dim3(55, 7, (rowsC+255)/256), 256, 0, stream>>>(dA, dEI56, dB, rowsC);
    k5b_idft<55,56><<<dim3(56, (rowsC+63)/64), 256, 0, stream>>>(dB, dEI56, b1, dHA,
                                                                 zc1, z0, 128, 56, 32, rowsC);
  }

  // ------------------- layer 2: so3_conv(28 -> 14), 32->64 -----------
  for (int z0 = 0; z0 < 128; z0 += zcF2) {
    int rowsC = zcF2*56;
    kf1_dftg<56,27><<<dim3(56, 2, (rowsC+255)/256), 256, 0, stream>>>(dHA, dEF56, dA,
                                                                      56, 128, z0, zcF2, rowsC);
    kf2_dfta<56,27><<<dim3(27, 2, (rowsC+255)/256), 256, 0, stream>>>(dA, dEF56, dB, rowsC);
    k8_wigfwd<<<3654, zcF2, 0, stream>>>(dB, dWF28T, dLMN14, dXSF, 56, zcF2, z0, 128);
  }
  k9_gemm3<32,64><<<tcnt[0], 256, 0, stream>>>(dXSF, w2, dTK2, dZSO);
  for (int z0 = 0; z0 < 256; z0 += zcI) {
    int rowsC = zcI*28;
    k4_wiginv<28,14><<<dim3(729, zcI/32), 256, 0, stream>>>(dZSO, dWI14T, dA, 256, z0, zcI);
    k5a_idft<27,28><<<dim3(27, 4, (rowsC+255)/256), 256, 0, stream>>>(dA, dEI28, dB, rowsC);
    k5b_idft<27,28><<<dim3(28, (rowsC+63)/64), 256, 0, stream>>>(dB, dEI28, b2, dHB,
                                                                 zcI, z0, 256, 28, 64, rowsC);
  }

  // ------------------- layer 3: so3_conv(14), 64->128 ----------------
  for (int z0 = 0; z0 < 256; z0 += zcF) {
    int rowsC = zcF*28;
    kf1_dftg<28,27><<<dim3(28, 2, (rowsC+255)/256), 256, 0, stream>>>(dHB, dEF28, dA,
                                                                      28, 256, z0, zcF, rowsC);
    kf2_dfta<28,27><<<dim3(27, 2, (rowsC+255)/256), 256, 0, stream>>>(dA, dEF28, dB, rowsC);
    k8_wigfwd<<<3654, zcF, 0, stream>>>(dB, dWF14T, dLMN14, dXSF, 28, zcF, z0, 256);
  }
  k9_gemm3<64,128><<<tcnt[1], 256, 0, stream>>>(dXSF, w3, dTK3, dZSO);
  for (int z0 = 0; z0 < 512; z0 += zcI) {
    int rowsC = zcI*28;
    k4_wiginv<28,14><<<dim3(729, zcI/32), 256, 0, stream>>>(dZSO, dWI14T, dA, 512, z0, zcI);
    k5a_idft<27,28><<<dim3(27, 4, (rowsC+255)/256), 256, 0, stream>>>(dA, dEI28, dB, rowsC);
    k5b_idft<27,28><<<dim3(28, (rowsC+63)/64), 256, 0, stream>>>(dB, dEI28, b3, dHA,
                                                                 zcI, z0, 512, 28, 128, rowsC);
  }

  // ------------------- layer 4: so3_conv(14), 128->64 ----------------
  for (int z0 = 0; z0 < 512; z0 += zcF) {
    int rowsC = zcF*28;
    kf1_dftg<28,27><<<dim3(28, 2, (rowsC+255)/256), 256, 0, stream>>>(dHA, dEF28, dA,
                                                                      28, 512, z0, zcF, rowsC);
    kf2_dfta<28,27><<<dim3(27, 2, (rowsC+255)/256), 256, 0, stream>>>(dA, dEF28, dB, rowsC);
    k8_wigfwd<<<3654, zcF, 0, stream>>>(dB, dWF14T, dLMN14, dXSF, 28, zcF, z0, 512);
  }
  k9_gemm3<128,64><<<tcnt[2], 256, 0, stream>>>(dXSF, w4, dTK4, dZSO);
  for (int z0 = 0; z0 < 256; z0 += zcI) {
    int rowsC = zcI*28;
    k4_wiginv<28,14><<<dim3(729, zcI/32), 256, 0, stream>>>(dZSO, dWI14T, dA, 256, z0, zcI);
    k5a_idft<27,28><<<dim3(27, 4, (rowsC+255)/256), 256, 0, stream>>>(dA, dEI28, dB, rowsC);
    k5b_idft<27,28><<<dim3(28, (rowsC+63)/64), 256, 0, stream>>>(dB, dEI28, b4, dHB,
                                                                 zcI, z0, 256, 28, 64, rowsC);
  }

  // ------------------- layer 5: so3_conv(14), 64->40 -----------------
  for (int z0 = 0; z0 < 256; z0 += zcF) {
    int rowsC = zcF*28;
    kf1_dftg<28,27><<<dim3(28, 2, (rowsC+255)/256), 256, 0, stream>>>(dHB, dEF28, dA,
                                                                      28, 256, z0, zcF, rowsC);
    kf2_dfta<28,27><<<dim3(27, 2, (rowsC+255)/256), 256, 0, stream>>>(dA, dEF28, dB, rowsC);
    k8_wigfwd<<<3654, zcF, 0, stream>>>(dB, dWF14T, dLMN14, dXSF, 28, zcF, z0, 256);
  }
  k9_gemm3<64,40><<<tcnt[3], 256, 0, stream>>>(dXSF, w5, dTK5, dZSO);
  {
    // Z = 160 in one chunk (T2 = 27 MB <= ab)
    int rowsC = 160*28;
    k4_wiginv<28,14><<<dim3(729, 5), 256, 0, stream>>>(dZSO, dWI14T, dA, 160, 0, 160);
    k5a_idft<27,28><<<dim3(27, 4, (rowsC+255)/256), 256, 0, stream>>>(dA, dEI28, dB, rowsC);
    k5b_idft<27,28><<<dim3(28, (rowsC+63)/64), 256, 0, stream>>>(dB, dEI28, b5, dHA,
                                                                 160, 0, 160, 28, 40, rowsC);
  }

  // ------------------- integrate + FC -------------------
  k10a_colsum<<<dim3(18, 16), 256, 0, stream>>>(dHA, dCp, 784, 4480, 49);
  k10a_fin<<<3, 64, 0, stream>>>(dCp, dUQW28, dS, 160, 28, 16);
  k10b_fc<<<1, 64, 0, stream>>>(dS, wout, bout, outp);
}